// Round 3
// baseline (386.954 us; speedup 1.0000x reference)
//
#include <hip/hip_runtime.h>
#include <hip/hip_bf16.h>
#include <stdint.h>

#define E_ 768
#define H_ 768
#define C_ 9
#define M_TOTAL 32768

typedef __attribute__((ext_vector_type(8))) __bf16 bf16x8;
typedef __attribute__((ext_vector_type(4))) float f32x4;
typedef __attribute__((ext_vector_type(4))) int i32x4;

static_assert(sizeof(bf16x8) == 16, "bf16x8 must be 16B");

__device__ __forceinline__ unsigned short f2bf(float f) {
    __hip_bfloat16 h = __float2bfloat16(f);
    return __builtin_bit_cast(unsigned short, h);
}

// ---------------------------------------------------------------------------
// Prep: repack W1 (fp32 [E][H]) into bf16 MFMA-B fragment cells:
//   W1f[((ntile*24 + t)*64 + lane)*8 + j] = bf16(W1[k][n])
//     n = ntile*16 + (lane&15), k = t*32 + (lane>>4)*8 + j
// and W2 (fp32 [H][C]) into bf16 B-fragment cells padded to 16 cols.
// Also zero the loss accumulator (d_out is poisoned before every launch).
// ---------------------------------------------------------------------------
__global__ void prep_kernel(const float* __restrict__ W1, const float* __restrict__ W2,
                            unsigned short* __restrict__ W1f, unsigned short* __restrict__ W2f,
                            float* __restrict__ loss_out)
{
    int tid = blockIdx.x * 256 + threadIdx.x;
    if (tid < 48 * 24 * 512) {
        int j    = tid & 7;
        int lane = (tid >> 3) & 63;
        int cell = tid >> 9;          // ntile*24 + t
        int t     = cell % 24;
        int ntile = cell / 24;
        int n = ntile * 16 + (lane & 15);
        int k = t * 32 + (lane >> 4) * 8 + j;
        W1f[tid] = f2bf(W1[k * H_ + n]);
    }
    if (tid < 24 * 512) {
        int j    = tid & 7;
        int lane = (tid >> 3) & 63;
        int t    = tid >> 9;
        int cls  = lane & 15;
        int k = t * 32 + (lane >> 4) * 8 + j;
        W2f[tid] = (cls < C_) ? f2bf(W2[k * C_ + cls]) : (unsigned short)0;
    }
    if (tid == 0) *loss_out = 0.0f;
}

// ---------------------------------------------------------------------------
// Fused head kernel, round 3. Block = 64 tokens x full H=768, 8 waves.
// Wave owns 4 mt x 6 nt (full N) -> acc[4][6] (AGPRs), ONE K-pass:
//   4 LDS A-reads feed 24 MFMAs per k-step (was 4:8).
// A staged in BK=96 double-buffered bf16-fragment pieces (2 x 12 KB) through
// regs; B fragments wave-private from W1f (L2 streams). LDS total 48 KB ->
// 2 blocks/CU (__launch_bounds__(512,4) forces VGPR<=128, acc -> AGPRs).
// Epilogue: 4 phases of 192 cols (Hsh 24 KB): tanh -> Hsh (A-frag layout),
// logit MFMAs on waves 0-3, then shuffle softmax + probs + loss atomic.
// ---------------------------------------------------------------------------
__launch_bounds__(512, 4)
__global__ void fused_head_kernel(const float* __restrict__ hidden,
                                  const unsigned short* __restrict__ W1f,
                                  const float* __restrict__ b1,
                                  const unsigned short* __restrict__ W2f,
                                  const float* __restrict__ b2,
                                  const int* __restrict__ labels,
                                  const int* __restrict__ epoch_p,
                                  float* __restrict__ probs,
                                  float* __restrict__ loss)
{
    __shared__ unsigned short Ast[2][4 * 3 * 512];   // 2 x 12 KB: A frag cells [mt][tl][lane*8]
    __shared__ unsigned short Hsh[6 * 4 * 512];      // 24 KB: h frag cells for one 192-col chunk

    const int tid  = threadIdx.x;
    const int w    = tid >> 6;     // wave 0..7
    const int lane = tid & 63;
    const int tok0 = blockIdx.x * 64;
    const int c16  = lane & 15;
    const int q    = lane >> 4;

    // ---- staging-thread invariants: 3 float4 loads/stores per stage ----
    const float* gsrc[3];
    int swaddr[3];
    #pragma unroll
    for (int it = 0; it < 3; ++it) {
        int idx = it * 512 + tid;        // 0..1535 float4 slots of a 64x96 piece
        int tk  = idx / 24;              // token row 0..63
        int kq  = idx - tk * 24;
        int kl  = kq * 4;                // k within stage, 0..92
        int mt = tk >> 4, tl = kl >> 5;
        int ln = (tk & 15) + 16 * ((kl >> 3) & 3);
        swaddr[it] = ((mt * 3 + tl) * 64 + ln) * 8 + (kl & 7);
        gsrc[it] = hidden + (size_t)(tok0 + tk) * E_ + kl;
    }

    // ---- B-fragment element offsets: wave-private n-tiles g = w*6+i ----
    uint32_t boff[6];
    #pragma unroll
    for (int i = 0; i < 6; ++i)
        boff[i] = (uint32_t)(((w * 6 + i) * 24) * 64 + lane) * 8;

    // ---- prologue: stage 0 into buf 0 ----
    {
        float4 v[3];
        #pragma unroll
        for (int it = 0; it < 3; ++it) v[it] = *(const float4*)(gsrc[it]);
        #pragma unroll
        for (int it = 0; it < 3; ++it) {
            ushort4 u = { f2bf(v[it].x), f2bf(v[it].y), f2bf(v[it].z), f2bf(v[it].w) };
            *(ushort4*)(&Ast[0][swaddr[it]]) = u;
        }
    }
    __syncthreads();

    const f32x4 zero4 = {0.0f, 0.0f, 0.0f, 0.0f};
    f32x4 acc[4][6];
    #pragma unroll
    for (int mt = 0; mt < 4; ++mt)
        #pragma unroll
        for (int i = 0; i < 6; ++i) acc[mt][i] = zero4;

    // ---- K loop: 8 stages x BK=96 (3 k-steps), double-buffered ----
    #pragma unroll
    for (int s = 0; s < 8; ++s) {
        float4 v[3];
        if (s < 7) {
            #pragma unroll
            for (int it = 0; it < 3; ++it)
                v[it] = *(const float4*)(gsrc[it] + (s + 1) * 96);
        }
        const unsigned short* Ab = Ast[s & 1];
        #pragma unroll
        for (int tl = 0; tl < 3; ++tl) {
            const int t = s * 3 + tl;
            bf16x8 af[4], bfr[6];
            #pragma unroll
            for (int i = 0; i < 6; ++i)
                bfr[i] = __builtin_bit_cast(bf16x8, *(const i32x4*)(W1f + boff[i] + t * 512));
            #pragma unroll
            for (int mt = 0; mt < 4; ++mt)
                af[mt] = __builtin_bit_cast(bf16x8, *(const i32x4*)(&Ab[((mt * 3 + tl) * 64 + lane) * 8]));
            #pragma unroll
            for (int mt = 0; mt < 4; ++mt)
                #pragma unroll
                for (int i = 0; i < 6; ++i)
                    acc[mt][i] = __builtin_amdgcn_mfma_f32_16x16x32_bf16(af[mt], bfr[i], acc[mt][i], 0, 0, 0);
        }
        if (s < 7) {
            unsigned short* An = Ast[(s + 1) & 1];
            #pragma unroll
            for (int it = 0; it < 3; ++it) {
                ushort4 u = { f2bf(v[it].x), f2bf(v[it].y), f2bf(v[it].z), f2bf(v[it].w) };
                *(ushort4*)(&An[swaddr[it]]) = u;
            }
        }
        __syncthreads();
    }

    // ---- epilogue: 4 phases of 192 cols. Waves 2c,2c+1 own phase c. ----
    f32x4 logit = zero4;   // waves 0-3: logits for rows w*16..+15
    const int myc = w >> 1;
    for (int c = 0; c < 4; ++c) {
        if (myc == c) {
            #pragma unroll
            for (int i = 0; i < 6; ++i) {
                int kloc = (w & 1) * 96 + i * 16 + c16;    // chunk-local h-col 0..191
                float b1v = b1[c * 192 + kloc];
                int t2 = kloc >> 5;
                int q2 = (kloc >> 3) & 3;
                int j  = kloc & 7;
                #pragma unroll
                for (int mt = 0; mt < 4; ++mt) {
                    #pragma unroll
                    for (int r = 0; r < 4; ++r) {
                        float z = acc[mt][i][r] + b1v;
                        // tanh(z) = 1 - 2/(exp(2z)+1), exp via native exp2
                        float e = exp2f(z * 2.8853900817779268f);
                        float th = 1.0f - 2.0f * __builtin_amdgcn_rcpf(e + 1.0f);
                        int lanep = (q * 4 + r) + 16 * q2;  // frag lane for row mt*16+q*4+r
                        Hsh[((t2 * 4 + mt) * 64 + lanep) * 8 + j] = f2bf(th);
                    }
                }
            }
        }
        __syncthreads();   // h chunk visible
        if (w < 4) {
            #pragma unroll
            for (int t2 = 0; t2 < 6; ++t2) {
                bf16x8 ha = __builtin_bit_cast(bf16x8, *(const i32x4*)(&Hsh[((t2 * 4 + w) * 64 + lane) * 8]));
                bf16x8 wb = __builtin_bit_cast(bf16x8, *(const i32x4*)(W2f + ((size_t)(c * 6 + t2) * 64 + lane) * 8));
                logit = __builtin_amdgcn_mfma_f32_16x16x32_bf16(ha, wb, logit, 0, 0, 0);
            }
        }
        __syncthreads();   // logit reads done before next phase rewrites Hsh
    }

    // ---- softmax over 9 classes (16-lane groups), probs store, loss ----
    if (w < 4) {
        const bool valid = (c16 < C_);
        const float b2v = valid ? b2[c16] : 0.0f;
        const int ep = epoch_p[0];
        float lsum = 0.0f;
        #pragma unroll
        for (int r = 0; r < 4; ++r) {
            float l = valid ? (logit[r] + b2v) : -3.0e38f;
            float m = l;
            #pragma unroll
            for (int d = 1; d < 16; d <<= 1)
                m = fmaxf(m, __shfl_xor(m, d, 64));
            float e = valid ? exp2f((l - m) * 1.44269504f) : 0.0f;
            float s = e;
            #pragma unroll
            for (int d = 1; d < 16; d <<= 1)
                s += __shfl_xor(s, d, 64);
            float p = e / s;
            int row = tok0 + w * 16 + q * 4 + r;
            if (valid) probs[(size_t)row * C_ + c16] = p;
            int lab = labels[row];
            if (valid && lab == c16) {
                float wgt = (ep <= 2) ? 1.0f : ((p > 0.7f) ? 1.0f : 0.0f);
                if (wgt > 0.0f)
                    lsum += (1.0f - exp2f(0.7f * log2f(p))) * (1.0f / 0.7f);
            }
        }
        #pragma unroll
        for (int d = 1; d < 64; d <<= 1)
            lsum += __shfl_xor(lsum, d, 64);
        if (lane == 0) atomicAdd(loss, lsum);
    }
}

// ---------------------------------------------------------------------------
extern "C" void kernel_launch(void* const* d_in, const int* in_sizes, int n_in,
                              void* d_out, int out_size, void* d_ws, size_t ws_size,
                              hipStream_t stream)
{
    const float* hidden = (const float*)d_in[0];
    const float* W1     = (const float*)d_in[1];
    const float* b1     = (const float*)d_in[2];
    const float* W2     = (const float*)d_in[3];
    const float* b2     = (const float*)d_in[4];
    const int*   labels = (const int*)d_in[5];
    const int*   epoch  = (const int*)d_in[6];

    float* probs = (float*)d_out;                       // [32768 x 9]
    float* loss  = probs + (size_t)M_TOTAL * C_;        // scalar at the end

    unsigned short* W1f = (unsigned short*)d_ws;        // 589824 bf16
    unsigned short* W2f = W1f + 48 * 24 * 512;          // 12288 bf16

    prep_kernel<<<2304, 256, 0, stream>>>(W1, W2, W1f, W2f, loss);
    fused_head_kernel<<<512, 512, 0, stream>>>(hidden, W1f, b1, W2f, b2,
                                               labels, epoch, probs, loss);
}